// Round 13
// baseline (363.653 us; speedup 1.0000x reference)
//
#include <hip/hip_runtime.h>
#include <hip/hip_bf16.h>

// ---------------------------------------------------------------------------
// FCOS head on MI355X.
//  - activations channels-last bf16, PADDED rows (1 zero row each side per
//    (level,b) chunk). Chunk starts: L0 b*1026, L1 8208+b*514, L2 12320+b*258.
//  - conv1d(K) == GEMM; BN folded into weights/bias on device.
//  - conv_tower v10: 2 waves (128 thr), block 128co x 256t, WAVE 128co x 128t
//    (acc 8x8 -> 256 VGPR, 1 wave/SIMD). Reads/FLOP cut 33% vs 128x64 wave:
//    per tap per wave 16 ds_read_b128 feed 64 MFMAs -> LDS service (771cy/CU)
//    fits under MFMA (1242cy/CU). W ring-3 LDS + X dbuf, ONE barrier/tap,
//    counted FIFO vmcnt (4/13/13 steady; 4/4/0 tail). LDS 58KB, 2 blocks/CU.
//  - conv_gemm (mix/iou): 128x128 2-phase pipeline (R11 version).
//  - LDS: linear dest + 16B-granule XOR swizzle on SOURCE addr and ds_read.
// ---------------------------------------------------------------------------

typedef __bf16 bf16x8 __attribute__((ext_vector_type(8)));
typedef float f32x4 __attribute__((ext_vector_type(4)));

__device__ __forceinline__ float bf2f(unsigned short u) {
    union { unsigned int i; float f; } c; c.i = ((unsigned int)u) << 16; return c.f;
}
__device__ __forceinline__ unsigned short f2bf(float f) {
    union { __hip_bfloat16 h; unsigned short u; } c; c.h = __float2bfloat16(f); return c.u;
}

__device__ __forceinline__ void gload16(const void* g, void* l) {
    __builtin_amdgcn_global_load_lds(
        (const __attribute__((address_space(1))) unsigned int*)g,
        (__attribute__((address_space(3))) unsigned int*)l,
        16, 0, 0);
}

// decode 128-wide column tile -> (rowstart = storage row of t=0 of chunk, t0, Tl)
__device__ __forceinline__ void tile_decode(int ct, int& rowstart, int& t0, int& Tl) {
    if (ct < 64)      { Tl = 1024; int b = ct >> 3;                 t0 = (ct & 7) << 7; rowstart = b * 1026 + 1; }
    else if (ct < 96) { Tl = 512;  int i = ct - 64; int b = i >> 2; t0 = (i & 3) << 7; rowstart = 8208 + b * 514 + 1; }
    else              { Tl = 256;  int i = ct - 96; int b = i >> 1; t0 = (i & 1) << 7; rowstart = 12320 + b * 258 + 1; }
}

// ---------------------------------------------------------------------------
// conv_tower v10: 128 threads (2 waves), block 128co x 256t, grid 448.
// ---------------------------------------------------------------------------
__global__ __launch_bounds__(128, 1)
void conv_tower(const unsigned short* __restrict__ X, int xstride, int ci_twstride,
                const unsigned short* __restrict__ W,
                const float* __restrict__ Bs,
                unsigned short* __restrict__ Y)
{
    __shared__ alignas(16) unsigned short Xb[2][17 * 512];   // 2 x 17 KB (272 rows)
    __shared__ alignas(16) unsigned short Wb[3][8 * 512];    // 3 x 8 KB (128co x 32ci)
    constexpr int XBSZ = 17 * 512;
    constexpr int WBSZ = 8 * 512;
    constexpr int XBYTES = XBSZ * 2;
    constexpr int WBYTES = WBSZ * 2;

    // XCD-contiguous remap: 448 = 8*56, bijective
    const int L = blockIdx.x;
    const int P = (L & 7) * 56 + (L >> 3);
    const int tt = P >> 3, sub = P & 7;
    const int tw = sub >> 2, co0 = (sub & 3) << 7;

    int rowstart;  // storage row of this 256-wide t-tile's first t
    if (tt < 32)      { rowstart = (tt >> 2) * 1026 + 1 + ((tt & 3) << 8); }
    else if (tt < 48) { int i = tt - 32; rowstart = 8208 + (i >> 1) * 514 + 1 + ((i & 1) << 8); }
    else              { rowstart = 12320 + (tt - 48) * 258 + 1; }

    const int tid = threadIdx.x, lane = tid & 63, wid = tid >> 6;   // wid 0,1
    const int lr = lane & 15, sr = lane >> 4;
    const int wt = wid << 7;   // wave t-offset: 0 / 128

    const unsigned short* Wp = W + (size_t)tw * 3145728;
    const float* Bp = Bs + tw * 2048;
    const int co_out0 = tw * 512 + co0;
    const int ci_off = tw * ci_twstride;

    // X staging: 9 gloads/wave (segs {2p+wid, p<8} + seg16 by both waves)
    const unsigned short* xga[9]; unsigned short* xl[9];
#pragma unroll
    for (int p = 0; p < 9; ++p) {
        int seg = (p < 8) ? (p * 2 + wid) : 16;
        xl[p] = (unsigned short*)Xb[0] + seg * 512;
        int row = seg * 16 + (lane >> 2);
        int sc = (lane & 3) ^ ((row >> 1) & 3);
        xga[p] = X + (size_t)(rowstart - 1 + row) * xstride + ci_off + sc * 8;
    }
    // W staging: 4 gloads/wave (segs wid*4+p); base (tap0,ks0); +tap*512+ks*32 at issue
    const unsigned short* wga[4]; unsigned short* wl[4];
#pragma unroll
    for (int p = 0; p < 4; ++p) {
        int seg = wid * 4 + p;
        wl[p] = (unsigned short*)Wb[0] + seg * 512;
        int row = seg * 16 + (lane >> 2);
        int sc = (lane & 3) ^ ((row >> 1) & 3);
        wga[p] = Wp + (size_t)(co0 + row) * 1536 + sc * 8;
    }

    // per-lane LDS byte offsets
    int aoff[8];
#pragma unroll
    for (int mi = 0; mi < 8; ++mi) {
        int ra = mi * 16 + lr;
        aoff[mi] = ra * 64 + (((sr ^ (ra >> 1)) & 3) << 4);
    }
    int boff[3][8];
#pragma unroll
    for (int kk = 0; kk < 3; ++kk)
#pragma unroll
        for (int ni = 0; ni < 8; ++ni) {
            int rb = wt + ni * 16 + lr + kk;
            boff[kk][ni] = rb * 64 + (((sr ^ (rb >> 1)) & 3) << 4);
        }

    f32x4 acc[8][8];
#pragma unroll
    for (int i = 0; i < 8; ++i)
#pragma unroll
        for (int j = 0; j < 8; ++j) acc[i][j] = (f32x4){0.f, 0.f, 0.f, 0.f};

    // prologue: X(0)->Xb[0], W(0)->Wb[0], W(1)->Wb[1]; drain; barrier
#pragma unroll
    for (int p = 0; p < 9; ++p) gload16(xga[p], xl[p]);
#pragma unroll
    for (int p = 0; p < 4; ++p) {
        gload16(wga[p],       wl[p]);
        gload16(wga[p] + 512, wl[p] + WBSZ);
    }
    asm volatile("s_waitcnt vmcnt(0)" ::: "memory");
    __builtin_amdgcn_s_barrier();

    // per-tap compute: 8 af + 8 bv ds_reads, 64 MFMAs (compiler lgkmcnt)
    auto TAP = [&](const char* wbuf, const char* xbuf, const int* boffk) {
        bf16x8 af[8], bv[8];
#pragma unroll
        for (int mi = 0; mi < 8; ++mi)
            af[mi] = *(const bf16x8*)(wbuf + aoff[mi]);
#pragma unroll
        for (int ni = 0; ni < 8; ++ni)
            bv[ni] = *(const bf16x8*)(xbuf + boffk[ni]);
#pragma unroll
        for (int mi = 0; mi < 8; ++mi)
#pragma unroll
            for (int ni = 0; ni < 8; ++ni)
                acc[mi][ni] = __builtin_amdgcn_mfma_f32_16x16x32_bf16(af[mi], bv[ni], acc[mi][ni], 0, 0, 0);
    };

    // steady K-steps k0 = 0..14 (taps 3k0..3k0+2); waits FIFO-derived.
    for (int k0 = 0; k0 < 15; ++k0) {
        const char* xbuf = (const char*)Xb[0] + (k0 & 1) * XBYTES;
        // ---- tap kk=0 (ring slot 0): stage W(3k0+2)->ring2, X(k0+1)->other buf
        asm volatile("s_waitcnt vmcnt(4)" ::: "memory");
        __builtin_amdgcn_s_barrier();
#pragma unroll
        for (int p = 0; p < 4; ++p)
            gload16(wga[p] + 1024 + k0 * 32, wl[p] + 2 * WBSZ);
#pragma unroll
        for (int p = 0; p < 9; ++p)
            gload16(xga[p] + (k0 + 1) * 32, xl[p] + ((k0 + 1) & 1) * XBSZ);
        TAP((const char*)Wb[0], xbuf, boff[0]);
        // ---- tap kk=1 (ring slot 1): stage W(3k0+3)->ring0
        asm volatile("s_waitcnt vmcnt(13)" ::: "memory");
        __builtin_amdgcn_s_barrier();
#pragma unroll
        for (int p = 0; p < 4; ++p)
            gload16(wga[p] + (k0 + 1) * 32, wl[p]);
        TAP((const char*)Wb[0] + WBYTES, xbuf, boff[1]);
        // ---- tap kk=2 (ring slot 2): stage W(3k0+4)->ring1
        asm volatile("s_waitcnt vmcnt(13)" ::: "memory");
        __builtin_amdgcn_s_barrier();
#pragma unroll
        for (int p = 0; p < 4; ++p)
            gload16(wga[p] + 512 + (k0 + 1) * 32, wl[p] + WBSZ);
        TAP((const char*)Wb[0] + 2 * WBYTES, xbuf, boff[2]);
    }
    // ---- k0 = 15 peeled (taps 45,46,47)
    {
        const char* xbuf = (const char*)Xb[0] + (15 & 1) * XBYTES;
        asm volatile("s_waitcnt vmcnt(4)" ::: "memory");
        __builtin_amdgcn_s_barrier();
#pragma unroll
        for (int p = 0; p < 4; ++p)
            gload16(wga[p] + 1024 + 15 * 32, wl[p] + 2 * WBSZ);   // W(47)->ring2
        TAP((const char*)Wb[0], xbuf, boff[0]);
        asm volatile("s_waitcnt vmcnt(4)" ::: "memory");
        __builtin_amdgcn_s_barrier();
        TAP((const char*)Wb[0] + WBYTES, xbuf, boff[1]);
        asm volatile("s_waitcnt vmcnt(0)" ::: "memory");
        __builtin_amdgcn_s_barrier();
        TAP((const char*)Wb[0] + 2 * WBYTES, xbuf, boff[2]);
    }

    // epilogue: bias + relu + bf16 store (C/D: col=lane&15 -> t, row=(lane>>4)*4+r -> co)
    const int r4 = sr * 4;
#pragma unroll
    for (int mi = 0; mi < 8; ++mi) {
        int co_l = mi * 16 + r4;
        float b0 = Bp[co0 + co_l + 0], b1 = Bp[co0 + co_l + 1];
        float b2 = Bp[co0 + co_l + 2], b3 = Bp[co0 + co_l + 3];
#pragma unroll
        for (int ni = 0; ni < 8; ++ni) {
            int t = wt + ni * 16 + lr;
            f32x4 a = acc[mi][ni];
            float v0 = fmaxf(a[0] + b0, 0.f), v1 = fmaxf(a[1] + b1, 0.f);
            float v2 = fmaxf(a[2] + b2, 0.f), v3 = fmaxf(a[3] + b3, 0.f);
            union { unsigned long long u; unsigned short s[4]; } pk2;
            pk2.s[0] = f2bf(v0); pk2.s[1] = f2bf(v1); pk2.s[2] = f2bf(v2); pk2.s[3] = f2bf(v3);
            *(unsigned long long*)(Y + (size_t)(rowstart + t) * 1024 + co_out0 + co_l) = pk2.u;
        }
    }
}

// ---------------------------------------------------------------------------
// conv_gemm (mix / iou): 128x128 tile, 2-phase pipelined (R11 version).
// ---------------------------------------------------------------------------
template<int KSIZE>
__global__ __launch_bounds__(256)
void conv_gemm(const unsigned short* __restrict__ X, int xstride, int ci0_base, int ci_twstride, int Cin,
               const unsigned short* __restrict__ W, int w_twstride,
               const float* __restrict__ Bs, int b_twstride,
               unsigned short* __restrict__ Y, int ystride, int co_twstride,
               int relu)
{
    constexpr int BM = 128, BN = 128, BK = 32;
    constexpr int NR = BN + KSIZE - 1;
    constexpr int XSEG = (NR * 64 + 1023) / 1024;
    constexpr int XPW  = (XSEG + 3) / 4;
    constexpr int WSEG = KSIZE * BM * 64 / 1024;
    constexpr int WPW  = WSEG / 4;
    __shared__ alignas(16) unsigned short Xs[2 * XSEG * 512];
    __shared__ alignas(16) unsigned short Ws[2 * WSEG * 512];

    const int tid = threadIdx.x;
    const int lane = tid & 63, wid = tid >> 6;
    int rowstart, t0, Tl;
    tile_decode(blockIdx.x, rowstart, t0, Tl);
    const int co0 = blockIdx.y * BM;
    const int tw = blockIdx.z;
    const int ci_off = ci0_base + tw * ci_twstride;
    const unsigned short* Wp = W + (size_t)tw * w_twstride;
    const float* Bp = Bs + tw * b_twstride;
    const int co_out0 = tw * co_twstride + co0;

    const int wm = (wid >> 1) * 64, wn = (wid & 1) * 64;
    const int lr = lane & 15;
    const int sr = lane >> 4;

    const unsigned short* xga[XPW]; unsigned short* xl[XPW];
#pragma unroll
    for (int p = 0; p < XPW; ++p) {
        int seg = (KSIZE == 3) ? ((p < 2) ? p * 4 + wid : 8) : (p * 4 + wid);
        xl[p] = Xs + seg * 512;
        int g = seg * 64 + lane;
        int row = g >> 2, s = (g & 3) ^ ((row >> 1) & 3);
        xga[p] = X + (size_t)(rowstart + t0 - (KSIZE >> 1) + row) * xstride + ci_off + s * 8;
    }
    const unsigned short* wga[WPW]; unsigned short* wl[WPW];
#pragma unroll
    for (int p = 0; p < WPW; ++p) {
        int seg = p * 4 + wid;
        wl[p] = Ws + seg * 512;
        int g = seg * 64 + lane;
        int row = g >> 2, s = (g & 3) ^ ((row >> 1) & 3);
        int co = row & (BM - 1), kk = row >> 7;
        wga[p] = Wp + (size_t)(co0 + co) * (KSIZE * Cin) + kk * Cin + s * 8;
    }

    f32x4 acc[4][4];
#pragma unroll
    for (int i = 0; i < 4; ++i)
#pragma unroll
        for (int j = 0; j < 4; ++j) acc[i][j] = (f32x4){0.f, 0.f, 0.f, 0.f};

    auto STAGE = [&](int buf) {
#pragma unroll
        for (int p = 0; p < XPW; ++p) { gload16(xga[p], xl[p] + buf * (XSEG * 512)); xga[p] += BK; }
#pragma unroll
        for (int p = 0; p < WPW; ++p) { gload16(wga[p], wl[p] + buf * (WSEG * 512)); wga[p] += BK; }
    };

    const int nk = Cin / BK;
    STAGE(0);
    int cur = 0;
    for (int ks = 0; ks < nk; ++ks) {
        if (ks + 1 < nk) {
            STAGE(cur ^ 1);
            if constexpr (KSIZE == 3) asm volatile("s_waitcnt vmcnt(9)" ::: "memory");
            else                      asm volatile("s_waitcnt vmcnt(4)" ::: "memory");
        } else {
            asm volatile("s_waitcnt vmcnt(0)" ::: "memory");
        }
        __builtin_amdgcn_s_barrier();

        const char* bXs = (const char*)Xs + cur * (XSEG * 1024);
        const char* bWs = (const char*)Ws + cur * (WSEG * 1024);
#pragma unroll
        for (int kk = 0; kk < KSIZE; ++kk) {
            bf16x8 af[4], bv[4];
#pragma unroll
            for (int mi = 0; mi < 4; ++mi) {
                int ra = kk * BM + wm + mi * 16 + lr;
                af[mi] = *(const bf16x8*)(bWs + ra * 64 + (((sr ^ (ra >> 1)) & 3) << 4));
                int rb = wn + mi * 16 + lr + kk;
                bv[mi] = *(const bf16x8*)(bXs + rb * 64 + (((sr ^ (rb >> 1)) & 3) << 4));
            }
#pragma unroll
            for (int mi = 0; mi < 4; ++mi)
#pragma unroll
                for (int ni = 0; ni < 4; ++ni)
                    acc[mi][ni] = __builtin_amdgcn_mfma_f32_16x16x32_bf16(af[mi], bv[ni], acc[mi][ni], 0, 0, 0);
        }
        __builtin_amdgcn_s_barrier();
        cur ^= 1;
    }

    const int r4 = (lane >> 4) * 4;
#pragma unroll
    for (int mi = 0; mi < 4; ++mi) {
        int co_l = wm + mi * 16 + r4;
        float b0 = Bp[co0 + co_l + 0], b1 = Bp[co0 + co_l + 1];
        float b2 = Bp[co0 + co_l + 2], b3 = Bp[co0 + co_l + 3];
#pragma unroll
        for (int ni = 0; ni < 4; ++ni) {
            int t = t0 + wn + ni * 16 + lr;
            f32x4 a = acc[mi][ni];
            float v0 = a[0] + b0, v1 = a[1] + b1, v2 = a[2] + b2, v3 = a[3] + b3;
            if (relu) {
                v0 = fmaxf(v0, 0.f); v1 = fmaxf(v1, 0.f);
                v2 = fmaxf(v2, 0.f); v3 = fmaxf(v3, 0.f);
            }
            union { unsigned long long u; unsigned short s[4]; } pk;
            pk.s[0] = f2bf(v0); pk.s[1] = f2bf(v1); pk.s[2] = f2bf(v2); pk.s[3] = f2bf(v3);
            *(unsigned long long*)(Y + (size_t)(rowstart + t) * ystride + co_out0 + co_l) = pk.u;
        }
    }
}

// ---------------------------------------------------------------------------
// zero the pad rows of all activation buffers
// ---------------------------------------------------------------------------
__global__ __launch_bounds__(256)
void zero_pads(unsigned short* __restrict__ act0, unsigned short* __restrict__ catA,
               unsigned short* __restrict__ catB, unsigned short* __restrict__ mixo,
               unsigned short* __restrict__ iouh)
{
    int c = blockIdx.x >> 1, side = blockIdx.x & 1;
    int start, Tl;
    if (c < 8)       { start = c * 1026;               Tl = 1024; }
    else if (c < 16) { start = 8208 + (c - 8) * 514;   Tl = 512;  }
    else             { start = 12320 + (c - 16) * 258; Tl = 256;  }
    size_t prow = start + (side ? Tl + 1 : 0);
    int tid = threadIdx.x;
    uint4 z = make_uint4(0u, 0u, 0u, 0u);
    if (tid < 64)  *(uint4*)(act0 + prow * 512 + tid * 8) = z;
    if (tid < 128) { *(uint4*)(catA + prow * 1024 + tid * 8) = z;
                     *(uint4*)(catB + prow * 1024 + tid * 8) = z; }
    if (tid >= 128 && tid < 192) *(uint4*)(mixo + prow * 512 + (tid - 128) * 8) = z;
    if (tid >= 192 && tid < 224) *(uint4*)(iouh + prow * 256 + (tid - 192) * 8) = z;
}

// ---------------------------------------------------------------------------
// input transpose: f32 [b][c][t] -> bf16 padded [row][c]
// ---------------------------------------------------------------------------
__global__ __launch_bounds__(256)
void transpose_in(const float* __restrict__ f0, const float* __restrict__ f1, const float* __restrict__ f2,
                  unsigned short* __restrict__ act0)
{
    __shared__ float tile[32][33];
    int bx = blockIdx.x;
    const float* src; int Tl, padbase, b, t0;
    if (bx < 256)      { src = f0; Tl = 1024; int i = bx;       b = i >> 5; t0 = (i & 31) << 5; padbase = b * 1026; }
    else if (bx < 384) { src = f1; Tl = 512;  int i = bx - 256; b = i >> 4; t0 = (i & 15) << 5; padbase = 8208 + b * 514; }
    else               { src = f2; Tl = 256;  int i = bx - 384; b = i >> 3; t0 = (i & 7)  << 5; padbase = 12320 + b * 258; }
    int c0 = blockIdx.y << 5;
    const float* sb = src + (size_t)b * 512 * Tl;
    int tl = threadIdx.x & 31, cl = threadIdx.x >> 5;
#pragma unroll
    for (int j = 0; j < 4; ++j) {
        int c = cl + j * 8;
        tile[c][tl] = sb[(size_t)(c0 + c) * Tl + t0 + tl];
    }
    __syncthreads();
    int cc = threadIdx.x & 31, tr0 = threadIdx.x >> 5;
    size_t base = (size_t)(padbase + 1 + t0) * 512 + c0;
#pragma unroll
    for (int j = 0; j < 4; ++j) {
        int tr = tr0 + j * 8;
        act0[base + (size_t)tr * 512 + cc] = f2bf(tile[cc][tr]);
    }
}

// ---------------------------------------------------------------------------
// weight prep: tower weights -> Wt[tw][l][co][kk][ci] bf16, BN scale folded
// ---------------------------------------------------------------------------
__global__ __launch_bounds__(256)
void prep_tower(const float* __restrict__ cls_w, const float* __restrict__ box_w,
                const float* __restrict__ cg, const float* __restrict__ cvv,
                const float* __restrict__ bg, const float* __restrict__ bvv,
                unsigned short* __restrict__ Wt)
{
    int idx = blockIdx.x * 256 + threadIdx.x;
    if (idx >= 2 * 4 * 512 * 3 * 512) return;
    int ci = idx & 511;
    int kk = (idx >> 9) % 3;
    int co = (idx / 1536) & 511;
    int l  = (idx / 786432) & 3;
    int tw = idx / 3145728;
    const float* w = tw ? box_w : cls_w;
    const float* g = tw ? bg : cg;
    const float* v = tw ? bvv : cvv;
    float s = g[l * 512 + co] * rsqrtf(v[l * 512 + co] + 1e-5f);
    float val = w[(((size_t)(l * 512 + co)) * 512 + ci) * 3 + kk] * s;
    Wt[idx] = f2bf(val);
}

// mix + iou1 weights, and all folded biases
__global__ __launch_bounds__(256)
void prep_misc(const float* mix_w, const float* mix_b, const float* mg, const float* mbeta, const float* mm, const float* mv,
               const float* iou_w1, const float* iou_b1, const float* ig, const float* ibeta, const float* im, const float* iv,
               const float* cls_b, const float* cg, const float* cbeta, const float* cm, const float* cv2,
               const float* box_b, const float* bg, const float* bbeta, const float* bm, const float* bv2,
               unsigned short* Wmix, unsigned short* Wiou, float* Bt, float* Bmix, float* Biou)
{
    int idx = blockIdx.x * 256 + threadIdx.x;
    if (idx < 524288) {
        int co = idx >> 10;
        float s = mg[co] * rsqrtf(mv[co] + 1e-5f);
        Wmix[idx] = f2bf(mix_w[idx] * s);
        return;
    }
    idx -= 524288;
    if (idx < 393216) {
        int ci = idx & 511, kk = (idx >> 9) % 3, co = idx / 1536;
        float s = ig[co] * rsqrtf(iv[co] + 1e-5f);
        Wiou[idx] = f2bf(iou_w1[((size_t)(co * 512 + ci)) * 3 + kk] * s);
        return;
    }
    idx -= 393216;
    if (idx < 4096) {
        int co = idx & 511, l = (idx >> 9) & 3, tw = idx >> 11;
        const float* g = tw ? bg : cg; const float* v = tw ? bv2 : cv2;
        const float* m = tw ? bm : cm; const float* be = tw ? bbeta : cbeta;
        const float* cb = tw ? box_b : cls_b;
        int o = l * 512 + co;
        float s = g[o] * rsqrtf(v[o] + 1e-5f);
        Bt[idx] = (cb[o] - m[o]) * s + be[o];
        return;
    }
    idx -= 4096;
    if (idx < 512) {
        float s = mg[idx] * rsqrtf(mv[idx] + 1e-5f);
        Bmix[idx] = (mix_b[idx] - mm[idx]) * s + mbeta[idx];
        return;
    }
    idx -= 512;
    if (idx < 256) {
        float s = ig[idx] * rsqrtf(iv[idx] + 1e-5f);
        Biou[idx] = (iou_b1[idx] - im[idx]) * s + ibeta[idx];
    }
}

// ---------------------------------------------------------------------------
// heads: one wave per position, weights hoisted to per-lane registers.
// ---------------------------------------------------------------------------
__global__ __launch_bounds__(256)
void heads_kernel(const unsigned short* __restrict__ catb, const unsigned short* __restrict__ iouh,
                  const float* __restrict__ lw, const float* __restrict__ lb,
                  const float* __restrict__ bw, const float* __restrict__ bb,
                  const float* __restrict__ iw, const float* __restrict__ ib,
                  const float* __restrict__ scales, float* __restrict__ out)
{
    const int lane = threadIdx.x & 63;
    const int wid = threadIdx.x >> 6;

    float lwr[24], bwr0[24], bwr1[24], iwr[4];
    {
        const float4* p = (const float4*)(lw + lane * 24);
#pragma unroll
        for (int q = 0; q < 6; ++q) {
            float4 v = p[q];
            lwr[q * 4 + 0] = v.x; lwr[q * 4 + 1] = v.y; lwr[q * 4 + 2] = v.z; lwr[q * 4 + 3] = v.w;
        }
        p = (const float4*)(bw + lane * 24);
#pragma unroll
        for (int q = 0; q < 6; ++q) {
            float4 v = p[q];
            bwr0[q * 4 + 0] = v.x; bwr0[q * 4 + 1] = v.y; bwr0[q * 4 + 2] = v.z; bwr0[q * 4 + 3] = v.w;
        }
        p = (const float4*)(bw + 1536 + lane * 24);
#pragma unroll
        for (int q = 0; q < 6; ++q) {
            float4 v = p[q];
            bwr1[q * 4 + 0] = v.x; bwr1[q * 4 + 1] = v.y; bwr1[q * 4 + 2] = v.z; bwr1[q * 4 + 3] = v.w;
        }
        float4 v = *(const float4*)(iw + lane * 4);
        iwr[0] = v.x; iwr[1] = v.y; iwr[2] = v.z; iwr[3] = v.w;
    }
    const float lb0 = lb[0], bb0 = bb[0], bb1 = bb[1], ib0 = ib[0];
    const float s0 = scales[0], s1 = scales[1], s2 = scales[2];

    for (int r = blockIdx.x * 4 + wid; r < 14336; r += gridDim.x * 4) {
        int tlog, roff, tgoff, padbase; float sc;
        if (r < 8192)       { tlog = 10; roff = 0;     tgoff = 0;    sc = s0; }
        else if (r < 12288) { tlog = 9;  roff = 8192;  tgoff = 1024; sc = s1; }
        else                { tlog = 8;  roff = 12288; tgoff = 1536; sc = s2; }
        int i = r - roff;
        int Tl = 1 << tlog;
        int b = i >> tlog, t = i & (Tl - 1);
        if (r < 8192)       padbase = b * 1026;
        else if (r < 12288) padbase = 8208 + b * 514;
        else                padbase = 12320 + b * 258;
        int prow = padbase + 1 + t;

        float al = 0.f, a0 = 0.f, a1 = 0.f, ai = 0.f;
        const unsigned short* base = catb + (size_t)prow * 1024 + lane * 8;
#pragma unroll
        for (int kk = 0; kk < 3; ++kk) {
            union { uint4 u; unsigned short s[8]; } cv, bvv;
            cv.u = *(const uint4*)(base + (kk - 1) * 1024);
            bvv.u = *(const uint4*)(base + (kk - 1) * 1024 + 512);
#pragma unroll
            for (int j = 0; j < 8; ++j) {
                float xc = bf2f(cv.s[j]);
                float xb = bf2f(bvv.s[j]);
                al = fmaf(xc, lwr[j * 3 + kk], al);
                a0 = fmaf(xb, bwr0[j * 3 + kk], a0);
                a1 = fmaf(xb, bwr1[j * 3 + kk], a1);
            }
        }
        {
            union { uint2 u; unsigned short s[4]; } hv;
            hv.u = *(const uint2*)(iouh + (size_t)prow * 256 + lane * 4);
#pragma unroll
            for (int j = 0; j < 4; ++j) ai = fmaf(bf2f(hv.s[j]), iwr[j], ai);
        }
#pragma unroll
        for (int off = 32; off > 0; off >>= 1) {
            al += __shfl_xor(al, off);
            a0 += __shfl_xor(a0, off);
            a1 += __shfl_xor(a1, off);
            ai += __shfl_xor(ai, off);
        }
        if (lane == 0) {
            int tg = tgoff + t;
            out[((size_t)b * 4 + 0) * 1792 + tg] = al + lb0;
            out[((size_t)b * 4 + 1) * 1792 + tg] = expf((a0 + bb0) * sc);
            out[((size_t)b * 4 + 2) * 1792 + tg] = expf((a1 + bb1) * sc);
            out[((size_t)b * 4 + 3) * 1792 + tg] = ai + ib0;
        }
    }
}

// ---------------------------------------------------------------------------
extern "C" void kernel_launch(void* const* d_in, const int* in_sizes, int n_in,
                              void* d_out, int out_size, void* d_ws, size_t ws_size,
                              hipStream_t stream)
{
    const float* f0       = (const float*)d_in[0];
    const float* f1       = (const float*)d_in[1];
    const float* f2       = (const float*)d_in[2];
    const float* cls_tw_w = (const float*)d_in[3];
    const float* cls_tw_b = (const float*)d_in[4];
    const float* cls_bn_g = (const float*)d_in[5];
    const float* cls_bn_b = (const float*)d_in[6];
    const float* cls_bn_m = (const float*)d_in[7];
    const float* cls_bn_v = (const float*)d_in[8];
    const float* box_tw_w = (const float*)d_in[9];
    const float* box_tw_b = (const float*)d_in[10];
    const float* box_bn_g = (const float*)d_in[11];
    const float* box_bn_b = (const float*)d_in[12];
    const float* box_bn_m = (const float*)d_in[13];
    const float* box_bn_v = (const float*)d_in[14];
    const float* logits_w = (const float*)d_in[15];
    const float* logits_b = (const float*)d_in[16];
    const float* bbox_w   = (const float*)d_in[17];
    const float* bbox_b   = (const float*)d_in[18];
    const float* mix_w    = (const float*)d_in[19];
    const float* mix_b    = (const float*)d_in[20];
    const float* mix_bn_g = (const float*)d_in[21];
    const float* mix_bn_b = (const float*)d_in[22];
    const float* mix_bn_m = (const float*)d_in[23];
    const float* mix_bn_v = (const float*)d_in[24];
    const float* iou_w1   = (const float*)d_in[25];
    const float* iou_b1   = (const float*)d_in[26];
    const float* iou_bn_g = (const float*)d_in[27];
    const float* iou_bn_b = (const float*)d_in[28];
    const float* iou_bn_m = (const float*)d_in[29];
    const float* iou_bn_v = (const float*)d_in[30];
    const float* iou_w2   = (const float*)d_in[31];
    const float* iou_b2   = (const float*)d_in[32];
    const float* scales   = (const float*)d_in[33];

    unsigned char* ws = (unsigned char*)d_ws;
    unsigned short* Wt   = (unsigned short*)(ws + 0);          // 12,582,912 B
    unsigned short* Wmix = (unsigned short*)(ws + 12582912);   //  1,048,576 B
    unsigned short* Wiou = (unsigned short*)(ws + 13631488);   //    786,432 B
    float*          Bt   = (float*)(ws + 14417920);
    float*          Bmix = (float*)(ws + 14434304);
    float*          Biou = (float*)(ws + 14436352);
    unsigned short* act0 = (unsigned short*)(ws + 14437376);   // 14400*512*2
    unsigned short* catA = (unsigned short*)(ws + 29182976);   // 14400*1024*2
    unsigned short* catB = (unsigned short*)(ws + 58674176);   // 14400*1024*2
    unsigned short* mixo = (unsigned short*)(ws + 88165376);   // 14400*512*2
    unsigned short* iouh = (unsigned short*)(ws + 102910976);  // 14400*256*2

    zero_pads<<<dim3(48), dim3(256), 0, stream>>>(act0, catA, catB, mixo, iouh);
    prep_tower<<<dim3(24576), dim3(256), 0, stream>>>(cls_tw_w, box_tw_w, cls_bn_g, cls_bn_v,
                                                      box_bn_g, box_bn_v, Wt);
    prep_misc<<<dim3(3603), dim3(256), 0, stream>>>(mix_w, mix_b, mix_bn_g, mix_bn_b, mix_bn_m, mix_bn_v,
                                                    iou_w1, iou_b1, iou_bn_g, iou_bn_b, iou_bn_m, iou_bn_v,
                                                    cls_tw_b, cls_bn_g, cls_bn_b, cls_bn_m, cls_bn_v,
                                                    box_tw_b, box_bn_g, box_bn_b, box_bn_m, box_bn_v,
                                                    Wmix, Wiou, Bt, Bmix, Biou);
    transpose_in<<<dim3(448, 16), dim3(256), 0, stream>>>(f0, f1, f2, act0);

    // towers: 4 layers; grid 448 = 56 t-tiles(256) x 4 co-tiles x 2 towers, 128 thr
    conv_tower<<<dim3(448), dim3(128), 0, stream>>>(act0, 512, 0,    Wt,            Bt,        catA);
    conv_tower<<<dim3(448), dim3(128), 0, stream>>>(catA, 1024, 512, Wt + 786432,  Bt + 512,  catB);
    conv_tower<<<dim3(448), dim3(128), 0, stream>>>(catB, 1024, 512, Wt + 1572864, Bt + 1024, catA);
    conv_tower<<<dim3(448), dim3(128), 0, stream>>>(catA, 1024, 512, Wt + 2359296, Bt + 1536, catB);
    // mix: 1x1 conv over concat(ct,bt) = catB rows, Cin=1024
    conv_gemm<1><<<dim3(112, 4, 1), 256, 0, stream>>>(catB, 1024, 0, 0, 1024,
                                                      Wmix, 0, Bmix, 0, mixo, 512, 0, 1);
    // iou tower: 3-conv 512->256
    conv_gemm<3><<<dim3(112, 2, 1), 256, 0, stream>>>(mixo, 512, 0, 0, 512,
                                                      Wiou, 0, Biou, 0, iouh, 256, 0, 1);
    // heads
    heads_kernel<<<dim3(896), dim3(256), 0, stream>>>(catB, iouh, logits_w, logits_b,
                                                      bbox_w, bbox_b, iou_w2, iou_b2, scales,
                                                      (float*)d_out);
}

// Round 14
// 282.518 us; speedup vs baseline: 1.2872x; 1.2872x over previous
//
#include <hip/hip_runtime.h>
#include <hip/hip_bf16.h>

// ---------------------------------------------------------------------------
// FCOS head on MI355X.  (REVERT to R11 best-known: 283 us)
//  - activations channels-last bf16, PADDED rows: each (level,b) chunk is
//    [1 zero pad row][Tl rows][1 zero pad row]. Chunk starts:
//      L0 (Tl=1024): b*1026      L1 (512): 8208+b*514     L2 (256): 12320+b*258
//    total 14384 storage rows (alloc 14400). Pads zeroed each call.
//  - conv1d(K) == GEMM; BN folded into weights/bias on device.
//  - conv_tower v8: 4 waves, block 256co x 128t, wave 128co x 64t. 48 taps.
//    W ring-3 LDS buffers, COUNTED vmcnt (never 0 mid-loop), X double-buffered
//    per K-step. ONE barrier per tap. LDS 66 KB -> 2 blocks/CU (grid 448,
//    XCD-bijective). ~897 TF/layer = plain-HIP structural ceiling (m97 class).
//  - conv_gemm (mix/iou): 128x128 2-phase pipeline.
//  - LDS: linear dest + 16B-granule XOR swizzle on SOURCE addr and ds_read.
// ---------------------------------------------------------------------------

typedef __bf16 bf16x8 __attribute__((ext_vector_type(8)));
typedef float f32x4 __attribute__((ext_vector_type(4)));

__device__ __forceinline__ float bf2f(unsigned short u) {
    union { unsigned int i; float f; } c; c.i = ((unsigned int)u) << 16; return c.f;
}
__device__ __forceinline__ unsigned short f2bf(float f) {
    union { __hip_bfloat16 h; unsigned short u; } c; c.h = __float2bfloat16(f); return c.u;
}

__device__ __forceinline__ void gload16(const void* g, void* l) {
    __builtin_amdgcn_global_load_lds(
        (const __attribute__((address_space(1))) unsigned int*)g,
        (__attribute__((address_space(3))) unsigned int*)l,
        16, 0, 0);
}

// decode 128-wide column tile -> (rowstart = storage row of t=0 of chunk, t0, Tl)
__device__ __forceinline__ void tile_decode(int ct, int& rowstart, int& t0, int& Tl) {
    if (ct < 64)      { Tl = 1024; int b = ct >> 3;                 t0 = (ct & 7) << 7; rowstart = b * 1026 + 1; }
    else if (ct < 96) { Tl = 512;  int i = ct - 64; int b = i >> 2; t0 = (i & 3) << 7; rowstart = 8208 + b * 514 + 1; }
    else              { Tl = 256;  int i = ct - 96; int b = i >> 1; t0 = (i & 1) << 7; rowstart = 12320 + b * 258 + 1; }
}

// ---------------------------------------------------------------------------
// conv_tower v8
// ---------------------------------------------------------------------------
__global__ __launch_bounds__(256, 2)
void conv_tower(const unsigned short* __restrict__ X, int xstride, int ci_twstride,
                const unsigned short* __restrict__ W,
                const float* __restrict__ Bs,
                unsigned short* __restrict__ Y)
{
    __shared__ alignas(16) unsigned short Xb[2][9 * 512];    // 2 x 9 KB (144 LDS rows)
    __shared__ alignas(16) unsigned short Wb[3][16 * 512];   // 3 x 16 KB (256 co rows, one tap)
    constexpr int XBSZ = 9 * 512;
    constexpr int WBSZ = 16 * 512;
    constexpr int XBYTES = XBSZ * 2;
    constexpr int WBYTES = WBSZ * 2;

    // XCD-contiguous remap: 448 = 8*56, bijective
    const int L = blockIdx.x;
    const int P = (L & 7) * 56 + (L >> 3);
    const int ct = P >> 2, sub = P & 3;
    const int tw = sub >> 1, co0 = (sub & 1) << 8;

    int rowstart, t0, Tl;
    tile_decode(ct, rowstart, t0, Tl);
    const int rtile = rowstart + t0;

    const int tid = threadIdx.x, lane = tid & 63, wid = tid >> 6;
    const int wco = (wid >> 1) << 7;   // 0 / 128
    const int wt  = (wid & 1) << 6;    // 0 / 64
    const int lr = lane & 15, sr = lane >> 4;

    const unsigned short* Wp = W + (size_t)tw * 3145728;
    const float* Bp = Bs + tw * 2048;
    const int co_out0 = tw * 512 + co0;
    const int ci_off = tw * ci_twstride;

    // X staging: 3 gloads/wave (segs wid, 4+wid, 8-by-all). LDS row r <-> t = t0+r-1.
    const unsigned short* xga[3]; unsigned short* xl[3];
#pragma unroll
    for (int p = 0; p < 3; ++p) {
        int seg = (p < 2) ? (p * 4 + wid) : 8;
        xl[p] = (unsigned short*)Xb[0] + seg * 512;
        int row = seg * 16 + (lane >> 2);
        int sc = (lane & 3) ^ ((row >> 1) & 3);
        xga[p] = X + (size_t)(rtile - 1 + row) * xstride + ci_off + sc * 8;
    }
    // W staging: 4 gloads/wave; base at (tap0, ks0); + tap*512 + ks*32 at issue
    const unsigned short* wga[4]; unsigned short* wl[4];
#pragma unroll
    for (int p = 0; p < 4; ++p) {
        int seg = p * 4 + wid;
        wl[p] = (unsigned short*)Wb[0] + seg * 512;
        int row = seg * 16 + (lane >> 2);
        int sc = (lane & 3) ^ ((row >> 1) & 3);
        wga[p] = Wp + (size_t)(co0 + row) * 1536 + sc * 8;
    }

    // precomputed per-lane LDS byte offsets
    int aoff[8];
#pragma unroll
    for (int mi = 0; mi < 8; ++mi) {
        int ra = wco + mi * 16 + lr;
        aoff[mi] = ra * 64 + (((sr ^ (ra >> 1)) & 3) << 4);
    }
    int boff[3][4];
#pragma unroll
    for (int kk = 0; kk < 3; ++kk)
#pragma unroll
        for (int ni = 0; ni < 4; ++ni) {
            int rb = wt + ni * 16 + lr + kk;
            boff[kk][ni] = rb * 64 + (((sr ^ (rb >> 1)) & 3) << 4);
        }

    f32x4 acc[8][4];
#pragma unroll
    for (int i = 0; i < 8; ++i)
#pragma unroll
        for (int j = 0; j < 4; ++j) acc[i][j] = (f32x4){0.f, 0.f, 0.f, 0.f};

    // prologue: X(0)->Xb[0], W(tap0 of ks0)->Wb[0], W(tap1 of ks0)->Wb[1]
#pragma unroll
    for (int p = 0; p < 3; ++p) gload16(xga[p], xl[p]);
#pragma unroll
    for (int p = 0; p < 4; ++p) {
        gload16(wga[p],       wl[p]);
        gload16(wga[p] + 512, wl[p] + WBSZ);
    }
    asm volatile("s_waitcnt vmcnt(0)" ::: "memory");
    __builtin_amdgcn_s_barrier();

    // main loop: 48 taps, fully unrolled. Per tap s (ONE barrier, at top):
    //   counted vmcnt (tap-s data retired; taps s+1.. stay in flight) -> barrier
    //   -> issue W(s+2) [+X(k0+1) at kk==0] -> ds_read 12 frags + 32 MFMA
    //      (compiler-scheduled fine-grained lgkmcnt).
#pragma unroll
    for (int s = 0; s < 48; ++s) {
        const int kk = s % 3, k0 = s / 3;
        // FIFO-derived counted waits: mid-loop kk==0 -> 4, else 7; tail 46/47 -> 4/0.
        if      (s == 47) asm volatile("s_waitcnt vmcnt(0)" ::: "memory");
        else if (s == 46) asm volatile("s_waitcnt vmcnt(4)" ::: "memory");
        else if (kk == 0) asm volatile("s_waitcnt vmcnt(4)" ::: "memory");
        else              asm volatile("s_waitcnt vmcnt(7)" ::: "memory");
        __builtin_amdgcn_s_barrier();

        // stage W for tap s+2 into ring[(s+2)%3]
        if (s + 2 <= 47) {
            const int u = s + 2, ut = u % 3, uk = u / 3;
#pragma unroll
            for (int p = 0; p < 4; ++p)
                gload16(wga[p] + ut * 512 + uk * 32, wl[p] + ut * WBSZ);
        }
        // stage X for K-step k0+1 into Xb[(k0+1)&1] (once per K-step)
        if (kk == 0 && k0 + 1 <= 15) {
#pragma unroll
            for (int p = 0; p < 3; ++p)
                gload16(xga[p] + (k0 + 1) * 32, xl[p] + ((k0 + 1) & 1) * XBSZ);
        }

        // fragments + MFMA (no manual lgkm drain / sched pinning / tail barrier)
        const char* wbuf = (const char*)Wb[0] + (s % 3) * WBYTES;
        const char* xbuf = (const char*)Xb[0] + (k0 & 1) * XBYTES;
        bf16x8 af[8], bv[4];
#pragma unroll
        for (int mi = 0; mi < 8; ++mi)
            af[mi] = *(const bf16x8*)(wbuf + aoff[mi]);
#pragma unroll
        for (int ni = 0; ni < 4; ++ni)
            bv[ni] = *(const bf16x8*)(xbuf + boff[kk][ni]);
#pragma unroll
        for (int mi = 0; mi < 8; ++mi)
#pragma unroll
            for (int ni = 0; ni < 4; ++ni)
                acc[mi][ni] = __builtin_amdgcn_mfma_f32_16x16x32_bf16(af[mi], bv[ni], acc[mi][ni], 0, 0, 0);
    }

    // epilogue: bias + relu + bf16 store (C/D: col=lane&15 -> t, row=(lane>>4)*4+r -> co)
    const int r4 = sr * 4;
#pragma unroll
    for (int mi = 0; mi < 8; ++mi) {
        int co_l = wco + mi * 16 + r4;
        float b0 = Bp[co0 + co_l + 0], b1 = Bp[co0 + co_l + 1];
        float b2 = Bp[co0 + co_l + 2], b3 = Bp[co0 + co_l + 3];
#pragma unroll
        for (int ni = 0; ni < 4; ++ni) {
            int t = wt + ni * 16 + lr;
            f32x4 a = acc[mi][ni];
            float v0 = fmaxf(a[0] + b0, 0.f), v1 = fmaxf(a[1] + b1, 0.f);
            float v2 = fmaxf(a[2] + b2, 0.f), v3 = fmaxf(a[3] + b3, 0.f);
            union { unsigned long long u; unsigned short s[4]; } pk2;
            pk2.s[0] = f2bf(v0); pk2.s[1] = f2bf(v1); pk2.s[2] = f2bf(v2); pk2.s[3] = f2bf(v3);
            *(unsigned long long*)(Y + (size_t)(rtile + t) * 1024 + co_out0 + co_l) = pk2.u;
        }
    }
}

// ---------------------------------------------------------------------------
// conv_gemm (mix / iou): 128x128 tile, 2-phase pipelined.
// ---------------------------------------------------------------------------
template<int KSIZE>
__global__ __launch_bounds__(256)
void conv_gemm(const unsigned short* __restrict__ X, int xstride, int ci0_base, int ci_twstride, int Cin,
               const unsigned short* __restrict__ W, int w_twstride,
               const float* __restrict__ Bs, int b_twstride,
               unsigned short* __restrict__ Y, int ystride, int co_twstride,
               int relu)
{
    constexpr int BM = 128, BN = 128, BK = 32;
    constexpr int NR = BN + KSIZE - 1;
    constexpr int XSEG = (NR * 64 + 1023) / 1024;
    constexpr int XPW  = (XSEG + 3) / 4;
    constexpr int WSEG = KSIZE * BM * 64 / 1024;
    constexpr int WPW  = WSEG / 4;
    __shared__ alignas(16) unsigned short Xs[2 * XSEG * 512];
    __shared__ alignas(16) unsigned short Ws[2 * WSEG * 512];

    const int tid = threadIdx.x;
    const int lane = tid & 63, wid = tid >> 6;
    int rowstart, t0, Tl;
    tile_decode(blockIdx.x, rowstart, t0, Tl);
    const int co0 = blockIdx.y * BM;
    const int tw = blockIdx.z;
    const int ci_off = ci0_base + tw * ci_twstride;
    const unsigned short* Wp = W + (size_t)tw * w_twstride;
    const float* Bp = Bs + tw * b_twstride;
    const int co_out0 = tw * co_twstride + co0;

    const int wm = (wid >> 1) * 64, wn = (wid & 1) * 64;
    const int lr = lane & 15;
    const int sr = lane >> 4;

    const unsigned short* xga[XPW]; unsigned short* xl[XPW];
#pragma unroll
    for (int p = 0; p < XPW; ++p) {
        int seg = (KSIZE == 3) ? ((p < 2) ? p * 4 + wid : 8) : (p * 4 + wid);
        xl[p] = Xs + seg * 512;
        int g = seg * 64 + lane;
        int row = g >> 2, s = (g & 3) ^ ((row >> 1) & 3);
        xga[p] = X + (size_t)(rowstart + t0 - (KSIZE >> 1) + row) * xstride + ci_off + s * 8;
    }
    const unsigned short* wga[WPW]; unsigned short* wl[WPW];
#pragma unroll
    for (int p = 0; p < WPW; ++p) {
        int seg = p * 4 + wid;
        wl[p] = Ws + seg * 512;
        int g = seg * 64 + lane;
        int row = g >> 2, s = (g & 3) ^ ((row >> 1) & 3);
        int co = row & (BM - 1), kk = row >> 7;
        wga[p] = Wp + (size_t)(co0 + co) * (KSIZE * Cin) + kk * Cin + s * 8;
    }

    f32x4 acc[4][4];
#pragma unroll
    for (int i = 0; i < 4; ++i)
#pragma unroll
        for (int j = 0; j < 4; ++j) acc[i][j] = (f32x4){0.f, 0.f, 0.f, 0.f};

    auto STAGE = [&](int buf) {
#pragma unroll
        for (int p = 0; p < XPW; ++p) { gload16(xga[p], xl[p] + buf * (XSEG * 512)); xga[p] += BK; }
#pragma unroll
        for (int p = 0; p < WPW; ++p) { gload16(wga[p], wl[p] + buf * (WSEG * 512)); wga[p] += BK; }
    };

    const int nk = Cin / BK;
    STAGE(0);
    int cur = 0;
    for (int ks = 0; ks < nk; ++ks) {
        if (ks + 1 < nk) {
            STAGE(cur ^ 1);
            if constexpr (KSIZE == 3) asm volatile("s_waitcnt vmcnt(9)" ::: "memory");
            else                      asm volatile("s_waitcnt vmcnt(4)" ::: "memory");
        } else {
            asm volatile("s_waitcnt vmcnt(0)" ::: "memory");
        }
        __builtin_amdgcn_s_barrier();

        const char* bXs = (const char*)Xs + cur * (XSEG * 1024);
        const char* bWs = (const char*)Ws + cur * (WSEG * 1024);
#pragma unroll
        for (int kk = 0; kk < KSIZE; ++kk) {
            bf16x8 af[4], bv[4];
#pragma unroll
            for (int mi = 0; mi < 4; ++mi) {
                int ra = kk * BM + wm + mi * 16 + lr;
                af[mi] = *(const bf16x8*)(bWs + ra * 64 + (((sr ^ (ra >> 1)) & 3) << 4));
                int rb = wn + mi * 16 + lr + kk;
                bv[mi] = *(const bf16x8*)(bXs + rb * 64 + (((sr ^ (rb >> 1)) & 3) << 4));
            }
#pragma unroll
            for (int mi = 0; mi < 4; ++mi)
#pragma unroll
                for (int ni = 0; ni < 4; ++ni)
                    acc[mi][ni] = __builtin_amdgcn_mfma_f32_16x16x32_bf16(af[mi], bv[ni], acc[mi][ni], 0, 0, 0);
        }
        __builtin_amdgcn_s_barrier();
        cur ^= 1;
    }

    const int r4 = (lane >> 4) * 4;
#pragma unroll
    for (int mi = 0; mi < 4; ++mi) {
        int co_l = wm + mi * 16 + r4;
        float b0 = Bp[co0 + co_l + 0], b1 = Bp[co0 + co_l + 1];
        float b2 = Bp[co0 + co_l + 2], b3 = Bp[co0 + co_l + 3];
#pragma unroll
        for (int ni = 0; ni < 4; ++ni) {
            int t = t0 + wn + ni * 16 + lr;
            f32x4 a = acc[mi][ni];
            float v0 = a[0] + b0, v1 = a[1] + b1, v2 = a[2] + b2, v3 = a[3] + b3;
            if (relu) {
                v0 = fmaxf(v0, 0.f); v1 = fmaxf(v1, 0.f);
                v2 = fmaxf(v2, 0.f); v3 = fmaxf(v3, 0.f);
            }
            union { unsigned long long u; unsigned short s[4]; } pk;
            pk.s[0] = f2bf(v0); pk.s[1] = f2bf(v1); pk.s[2] = f2bf(v2); pk.s[3] = f2bf(v3);
            *(unsigned long long*)(Y + (size_t)(rowstart + t) * ystride + co_out0 + co_l) = pk.u;
        }
    }
}

// ---------------------------------------------------------------------------
// zero the pad rows of all activation buffers
// ---------------------------------------------------------------------------
__global__ __launch_bounds__(256)
void zero_pads(unsigned short* __restrict__ act0, unsigned short* __restrict__ catA,
               unsigned short* __restrict__ catB, unsigned short* __restrict__ mixo,
               unsigned short* __restrict__ iouh)
{
    int c = blockIdx.x >> 1, side = blockIdx.x & 1;
    int start, Tl;
    if (c < 8)       { start = c * 1026;               Tl = 1024; }
    else if (c < 16) { start = 8208 + (c - 8) * 514;   Tl = 512;  }
    else             { start = 12320 + (c - 16) * 258; Tl = 256;  }
    size_t prow = start + (side ? Tl + 1 : 0);
    int tid = threadIdx.x;
    uint4 z = make_uint4(0u, 0u, 0u, 0u);
    if (tid < 64)  *(uint4*)(act0 + prow * 512 + tid * 8) = z;
    if (tid < 128) { *(uint4*)(catA + prow * 1024 + tid * 8) = z;
                     *(uint4*)(catB + prow * 1024 + tid * 8) = z; }
    if (tid >= 128 && tid < 192) *(uint4*)(mixo + prow * 512 + (tid - 128) * 8) = z;
    if (tid >= 192 && tid < 224) *(uint4*)(iouh + prow * 256 + (tid - 192) * 8) = z;
}

// ---------------------------------------------------------------------------
// input transpose: f32 [b][c][t] -> bf16 padded [row][c]
// ---------------------------------------------------------------------------
__global__ __launch_bounds__(256)
void transpose_in(const float* __restrict__ f0, const float* __restrict__ f1, const float* __restrict__ f2,
                  unsigned short* __restrict__ act0)
{
    __shared__ float tile[32][33];
    int bx = blockIdx.x;
    const float* src; int Tl, padbase, b, t0;
    if (bx < 256)      { src = f0; Tl = 1024; int i = bx;       b = i >> 5; t0 = (i & 31) << 5; padbase = b * 1026; }
    else if (bx < 384) { src = f1; Tl = 512;  int i = bx - 256; b = i >> 4; t0 = (i & 15) << 5; padbase = 8208 + b * 514; }
    else               { src = f2; Tl = 256;  int i = bx - 384; b = i >> 3; t0 = (i & 7)  << 5; padbase = 12320 + b * 258; }
    int c0 = blockIdx.y << 5;
    const float* sb = src + (size_t)b * 512 * Tl;
    int tl = threadIdx.x & 31, cl = threadIdx.x >> 5;
#pragma unroll
    for (int j = 0; j < 4; ++j) {
        int c = cl + j * 8;
        tile[c][tl] = sb[(size_t)(c0 + c) * Tl + t0 + tl];
    }
    __syncthreads();
    int cc = threadIdx.x & 31, tr0 = threadIdx.x >> 5;
    size_t base = (size_t)(padbase + 1 + t0) * 512 + c0;
#pragma unroll
    for (int j = 0; j < 4; ++j) {
        int tr = tr0 + j * 8;
        act0[base + (size_t)tr * 512 + cc] = f2bf(tile[cc][tr]);
    }
}

// ---------------------------------------------------------------------------
// weight prep: tower weights -> Wt[tw][l][co][kk][ci] bf16, BN scale folded
// ---------------------------------------------------------------------------
__global__ __launch_bounds__(256)
void prep_tower(const float* __restrict__ cls_w, const float* __restrict__ box_w,
                const float* __restrict__ cg, const float* __restrict__ cvv,
                const float* __restrict__ bg, const float* __restrict__ bvv,
                unsigned short* __restrict__ Wt)
{
    int idx = blockIdx.x * 256 + threadIdx.x;
    if (idx >= 2 * 4 * 512 * 3 * 512) return;
    int ci = idx & 511;
    int kk = (idx >> 9) % 3;
    int co = (idx / 1536) & 511;
    int l  = (idx / 786432) & 3;
    int tw = idx / 3145728;
    const float* w = tw ? box_w : cls_w;
    const float* g = tw ? bg : cg;
    const float* v = tw ? bvv : cvv;
    float s = g[l * 512 + co] * rsqrtf(v[l * 512 + co] + 1e-5f);
    float val = w[(((size_t)(l * 512 + co)) * 512 + ci) * 3 + kk] * s;
    Wt[idx] = f2bf(val);
}

// mix + iou1 weights, and all folded biases
__global__ __launch_bounds__(256)
void prep_misc(const float* mix_w, const float* mix_b, const float* mg, const float* mbeta, const float* mm, const float* mv,
               const float* iou_w1, const float* iou_b1, const float* ig, const float* ibeta, const float* im, const float* iv,
               const float* cls_b, const float* cg, const float* cbeta, const float* cm, const float* cv2,
               const float* box_b, const float* bg, const float* bbeta, const float* bm, const float* bv2,
               unsigned short* Wmix, unsigned short* Wiou, float* Bt, float* Bmix, float* Biou)
{
    int idx = blockIdx.x * 256 + threadIdx.x;
    if (idx < 524288) {
        int co = idx >> 10;
        float s = mg[co] * rsqrtf(mv[co] + 1e-5f);
        Wmix[idx] = f2bf(mix_w[idx] * s);
        return;
    }
    idx -= 524288;
    if (idx < 393216) {
        int ci = idx & 511, kk = (idx >> 9) % 3, co = idx / 1536;
        float s = ig[co] * rsqrtf(iv[co] + 1e-5f);
        Wiou[idx] = f2bf(iou_w1[((size_t)(co * 512 + ci)) * 3 + kk] * s);
        return;
    }
    idx -= 393216;
    if (idx < 4096) {
        int co = idx & 511, l = (idx >> 9) & 3, tw = idx >> 11;
        const float* g = tw ? bg : cg; const float* v = tw ? bv2 : cv2;
        const float* m = tw ? bm : cm; const float* be = tw ? bbeta : cbeta;
        const float* cb = tw ? box_b : cls_b;
        int o = l * 512 + co;
        float s = g[o] * rsqrtf(v[o] + 1e-5f);
        Bt[idx] = (cb[o] - m[o]) * s + be[o];
        return;
    }
    idx -= 4096;
    if (idx < 512) {
        float s = mg[idx] * rsqrtf(mv[idx] + 1e-5f);
        Bmix[idx] = (mix_b[idx] - mm[idx]) * s + mbeta[idx];
        return;
    }
    idx -= 512;
    if (idx < 256) {
        float s = ig[idx] * rsqrtf(iv[idx] + 1e-5f);
        Biou[idx] = (iou_b1[idx] - im[idx]) * s + ibeta[idx];
    }
}

// ---------------------------------------------------------------------------
// heads: one wave per position, weights hoisted to per-lane registers.
// ---------------------------------------------------------------------------
__global__ __launch_bounds__(256)
void heads_kernel(const unsigned short* __restrict__ catb, const unsigned short* __restrict__ iouh,
                  const float* __restrict__ lw, const float* __restrict__ lb,
                  const float* __restrict__ bw, const float* __restrict__ bb,
                  const float* __restrict__ iw, const float* __restrict__ ib,
                  const float* __restrict__ scales, float* __restrict__ out)
{
    const int lane = threadIdx.x & 63;
    const int wid = threadIdx.x >> 6;

    float lwr[24], bwr0[24], bwr1[24], iwr[4];
    {
        const float4* p = (const float4*)(lw + lane * 24);
#pragma unroll
        for (int q = 0; q < 6; ++q) {
            float4 v = p[q];
            lwr[q * 4 + 0] = v.x; lwr[q * 4 + 1] = v.y; lwr[q * 4 + 2] = v.z; lwr[q * 4 + 3] = v.w;
        }
        p = (const float4*)(bw + lane * 24);
#pragma unroll
        for (int q = 0; q < 6; ++q) {
            float4 v = p[q];
            bwr0[q * 4 + 0] = v.x; bwr0[q * 4 + 1] = v.y; bwr0[q * 4 + 2] = v.z; bwr0[q * 4 + 3] = v.w;
        }
        p = (const float4*)(bw + 1536 + lane * 24);
#pragma unroll
        for (int q = 0; q < 6; ++q) {
            float4 v = p[q];
            bwr1[q * 4 + 0] = v.x; bwr1[q * 4 + 1] = v.y; bwr1[q * 4 + 2] = v.z; bwr1[q * 4 + 3] = v.w;
        }
        float4 v = *(const float4*)(iw + lane * 4);
        iwr[0] = v.x; iwr[1] = v.y; iwr[2] = v.z; iwr[3] = v.w;
    }
    const float lb0 = lb[0], bb0 = bb[0], bb1 = bb[1], ib0 = ib[0];
    const float s0 = scales[0], s1 = scales[1], s2 = scales[2];

    for (int r = blockIdx.x * 4 + wid; r < 14336; r += gridDim.x * 4) {
        int tlog, roff, tgoff, padbase; float sc;
        if (r < 8192)       { tlog = 10; roff = 0;     tgoff = 0;    sc = s0; }
        else if (r < 12288) { tlog = 9;  roff = 8192;  tgoff = 1024; sc = s1; }
        else                { tlog = 8;  roff = 12288; tgoff = 1536; sc = s2; }
        int i = r - roff;
        int Tl = 1 << tlog;
        int b = i >> tlog, t = i & (Tl - 1);
        if (r < 8192)       padbase = b * 1026;
        else if (r < 12288) padbase = 8208 + b * 514;
        else                padbase = 12320 + b * 258;
        int prow = padbase + 1 + t;

        float al = 0.f, a0 = 0.f, a1 = 0.f, ai = 0.f;
        const unsigned short* base = catb + (size_t)prow * 1024 + lane * 8;
#pragma unroll
        for (int kk = 0; kk < 3; ++kk) {
            union { uint4 u; unsigned short s[8]; } cv, bvv;
            cv.u = *(const uint4*)(base + (kk - 1) * 1024);
            bvv.u = *(const uint4*)(base + (kk - 1) * 1024 + 512);
#pragma unroll
            for (int j = 0; j < 8; ++j) {
                float xc = bf2f(cv.s[j]);
                float xb = bf2f(bvv.s[j]);
                al = fmaf(xc, lwr[j * 3 + kk], al);
                a0 = fmaf(xb, bwr0[j * 3 + kk], a0);
                a1 = fmaf(xb, bwr1[j * 3 + kk], a1);
            }
        }
        {
            union { uint2 u; unsigned short s[4]; } hv;
            hv.u = *(const uint2*)(iouh + (size_t)prow * 256 + lane * 4);
#pragma unroll
            for (int j = 0; j < 4; ++j) ai = fmaf(bf2f(hv.s[j]), iwr[j], ai);
        }
#pragma unroll
        for (int off = 32; off > 0; off >>= 1) {
            al += __shfl_xor(al, off);
            a0 += __shfl_xor(a0, off);
            a1 += __shfl_xor(a1, off);
            ai += __shfl_xor(ai, off);
        }
        if (lane == 0) {
            int tg = tgoff + t;
            out[((size_t)b * 4 + 0) * 1792 + tg] = al + lb0;
            out[((size_t)b * 4 + 1) * 1792 + tg] = expf((a0 + bb0) * sc);
            out[((size_t)b * 4 + 2) * 1792 + tg] = expf((a1 + bb1) * sc);
            out[((size_t)b * 4 + 3) * 1792 + tg] = ai + ib0;
        }
    }
}

// ---------------------------------------------------------------------------
extern "C" void kernel_launch(void* const* d_in, const int* in_sizes, int n_in,
                              void* d_out, int out_size, void* d_ws, size_t ws_size,
                              hipStream_t stream)
{
    const float* f0       = (const float*)d_in[0];
    const float* f1       = (const float*)d_in[1];
    const float* f2       = (const float*)d_in[2];
    const float* cls_tw_w = (const float*)d_in[3];
    const float* cls_tw_b = (const float*)d_in[4];
    const float* cls_bn_g = (const float*)d_in[5];
    const float* cls_bn_b = (const float*)d_in[6];
    const float* cls_bn_m = (const float*)d_in[7];
    const float* cls_bn_v = (const float*)d_in[8];
    const float* box_tw_w = (const float*)d_in[9];
    const float* box_tw_b = (const float*)d_in[10];
    const float* box_bn_g = (const float*)d_in[11];
    const float* box_bn_b = (const float*)d_in[12];
    const float* box_bn_m = (const float*)d_in[13];
    const float* box_bn_v = (const float*)d_in[14];
    const float* logits_w = (const float*)d_in[15];
    const float* logits_b = (const float*)d_in[16];
    const float* bbox_w   = (const float*)d_in[17];
    const float* bbox_b   = (const float*)d_in[18];
    const float* mix_w    = (const float*)d_in[19];
    const float* mix_b    = (const float*)d_in[20];
    const float* mix_bn_g = (const float*)d_in[21];
    const float* mix_bn_b = (const float*)d_in[22];
    const float* mix_bn_m = (const float*)d_in[23];
    const float* mix_bn_v = (const float*)d_in[24];
    const float* iou_w1   = (const float*)d_in[25];
    const float* iou_b1   = (const float*)d_in[26];
    const float* iou_bn_g = (const float*)d_in[27];
    const float* iou_bn_b = (const float*)d_in[28];
    const float* iou_bn_m = (const float*)d_in[29];
    const float* iou_bn_v = (const float*)d_in[30];
    const float* iou_w2   = (const float*)d_in[31];
    const float* iou_b2   = (const float*)d_in[32];
    const float* scales   = (const float*)d_in[33];

    unsigned char* ws = (unsigned char*)d_ws;
    unsigned short* Wt   = (unsigned short*)(ws + 0);          // 12,582,912 B
    unsigned short* Wmix = (unsigned short*)(ws + 12582912);   //  1,048,576 B
    unsigned short* Wiou = (unsigned short*)(ws + 13631488);   //    786,432 B
    float*          Bt   = (float*)(ws + 14417920);
    float*          Bmix = (float*)(ws + 14434304);
    float*          Biou = (float*)(ws + 14436352);
    unsigned short* act0 = (unsigned short*)(ws + 14437376);   // 14400*512*2
    unsigned short* catA = (unsigned short*)(ws + 29182976);   // 14400*1024*2
    unsigned short* catB = (unsigned short*)(ws + 58674176);   // 14400*1024*2
    unsigned short* mixo = (unsigned short*)(ws + 88165376);   // 14400*512*2
    unsigned short* iouh = (unsigned short*)(ws + 102910976);  // 14400*256*2

    zero_pads<<<dim3(48), dim3(256), 0, stream>>>(act0, catA, catB, mixo, iouh);
    prep_tower<<<dim3(24576), dim3(256), 0, stream>>>(cls_tw_w, box_tw_w, cls_bn_g, cls_bn_v,
                                                      box_bn_g, box_bn_v, Wt);
    prep_misc<<<dim3(3603), dim3(256), 0, stream>>>(mix_w, mix_b, mix_bn_g, mix_bn_b, mix_bn_m, mix_bn_v,
                                                    iou_w1, iou_b1, iou_bn_g, iou_bn_b, iou_bn_m, iou_bn_v,
                                                    cls_tw_b, cls_bn_g, cls_bn_b, cls_bn_m, cls_bn_v,
                                                    box_tw_b, box_bn_g, box_bn_b, box_bn_m, box_bn_v,
                                                    Wmix, Wiou, Bt, Bmix, Biou);
    transpose_in<<<dim3(448, 16), dim3(256), 0, stream>>>(f0, f1, f2, act0);

    // towers: 4 layers; grid 448 = 112 t-tiles(128) x 2 co-halves x 2 towers -> 2 blocks/CU
    conv_tower<<<dim3(448), dim3(256), 0, stream>>>(act0, 512, 0,    Wt,            Bt,        catA);
    conv_tower<<<dim3(448), dim3(256), 0, stream>>>(catA, 1024, 512, Wt + 786432,  Bt + 512,  catB);
    conv_tower<<<dim3(448), dim3(256), 0, stream>>>(catB, 1024, 512, Wt + 1572864, Bt + 1024, catA);
    conv_tower<<<dim3(448), dim3(256), 0, stream>>>(catA, 1024, 512, Wt + 2359296, Bt + 1536, catB);
    // mix: 1x1 conv over concat(ct,bt) = catB rows, Cin=1024
    conv_gemm<1><<<dim3(112, 4, 1), 256, 0, stream>>>(catB, 1024, 0, 0, 1024,
                                                      Wmix, 0, Bmix, 0, mixo, 512, 0, 1);
    // iou tower: 3-conv 512->256
    conv_gemm<3><<<dim3(112, 2, 1), 256, 0, stream>>>(mixo, 512, 0, 0, 512,
                                                      Wiou, 0, Biou, 0, iouh, 256, 0, 1);
    // heads
    heads_kernel<<<dim3(896), dim3(256), 0, stream>>>(catB, iouh, logits_w, logits_b,
                                                      bbox_w, bbox_b, iou_w2, iou_b2, scales,
                                                      (float*)d_out);
}